// Round 7
// baseline (150.895 us; speedup 1.0000x reference)
//
#include <hip/hip_runtime.h>
#include <hip/hip_bf16.h>

// SampleContrastiveLoss on MI355X — round 4 design (3rd resubmit; rounds 4-6
// were broker GPUAcquisitionTimeouts, kernel never ran).
// N = 16384, D = 128. den_i = sum_{j masked} exp(sim_ij / T).
// Deltas vs round 3:
//  * gemm: NO LDS, no barriers. A (64 rows) in VGPRs for the whole block;
//    each wave owns distinct 16-col strips of the compacted B and loads its
//    MFMA B-fragments straight from global (L2-resident, co-resident blocks
//    share the same col-slice via jsl = bid&3). 4 blocks/CU (was 2).
//  * final: single kernel, last-block ticket does the divide (one launch less).
//
// ws layout:
//   [0,      4 MB)   n0b  bf16 [N][128]
//   [4 MB,   8 MB)   Bc   bf16 [N][128]  (compacted masked n1 rows, scaled)
//   [8 MB, ...)      diag f32[N] | maskf f32[N] | wc f32[N] | den f32[N]
//                    | pos i32[N] | {cnt i32, ticket i32, Lsum f64, Csum f64}

#define DD 128
#define INV_T 14.285714285714286f
#define C_EXP2 20.6099291555566f   // INV_T * log2(e)
#define JSL 4                      // col-slices; grid = (N/64)*JSL = 1024

typedef __attribute__((ext_vector_type(8))) short bf16x8; // 8 bf16 = 4 VGPR
typedef __attribute__((ext_vector_type(4))) float f32x4;
typedef unsigned short u16;
typedef unsigned char u8;

__device__ __forceinline__ u16 f2bf(float x) {   // RNE f32->bf16
    union { float f; unsigned u; } v; v.f = x;
    unsigned r = v.u + 0x7fffu + ((v.u >> 16) & 1u);
    return (u16)(r >> 16);
}

__device__ __forceinline__ float fast_exp2(float x) {
#if __has_builtin(__builtin_amdgcn_exp2f)
    return __builtin_amdgcn_exp2f(x);     // raw v_exp_f32
#else
    return exp2f(x);
#endif
}

// ---- mask dtype detect + maskf/wc/den init + block-scan compaction ------
// bool-as-u8: bytes at p%4!=0 in the first 4KB are ~50% nonzero.
// int32 0/1 LE: those bytes are all zero. Every block derives the same flag.
__global__ __launch_bounds__(256) void prep_kernel(
        const u8* __restrict__ mraw, float* __restrict__ maskf,
        float* __restrict__ wc, float* __restrict__ den,
        int* __restrict__ pos, int* __restrict__ cnt, int n) {
    __shared__ int s_any;
    __shared__ int s_wsum[4];
    __shared__ int s_base;
    if (threadIdx.x == 0) s_any = 0;
    __syncthreads();
    int local = 0;
    #pragma unroll
    for (int q = 0; q < 16; ++q) {
        const int p = threadIdx.x * 16 + q;
        if ((p & 3) && mraw[p]) local = 1;
    }
    if (local) atomicOr(&s_any, 1);
    __syncthreads();
    const bool is_u8 = (s_any != 0);
    const int* mi = (const int*)mraw;

    const int i = blockIdx.x * 256 + threadIdx.x;
    const int v = is_u8 ? (int)mraw[i] : mi[i];
    const int m = v ? 1 : 0;
    maskf[i] = (float)m;
    wc[i]   = 0.0f;
    den[i]  = 0.0f;

    const int wave = threadIdx.x >> 6, lane = threadIdx.x & 63;
    const unsigned long long bal = __ballot(m);
    const int wprefix = __popcll(bal & ((1ULL << lane) - 1ULL));
    const int wtotal  = __popcll(bal);
    if (lane == 0) s_wsum[wave] = wtotal;
    __syncthreads();
    if (threadIdx.x == 0)
        s_base = atomicAdd(cnt, s_wsum[0] + s_wsum[1] + s_wsum[2] + s_wsum[3]);
    __syncthreads();
    int wbase = 0;
    #pragma unroll
    for (int w = 0; w < 4; ++w)
        if (w < wave) wbase += s_wsum[w];
    pos[i] = m ? (s_base + wbase + wprefix) : -1;
}

// ---- per-row L2 normalize; write A (bf16), scatter masked scaled B ------
__global__ __launch_bounds__(256) void norm_kernel(
        const float* __restrict__ f0, const float* __restrict__ f1,
        const int* __restrict__ pos,
        u16* __restrict__ n0b, u16* __restrict__ Bc, float* __restrict__ wc,
        float* __restrict__ diag) {
    const int wave = threadIdx.x >> 6, lane = threadIdx.x & 63;
    const int i = blockIdx.x * 4 + wave;
    const float2 a = *(const float2*)(f0 + (size_t)i * DD + lane * 2);
    const float2 b = *(const float2*)(f1 + (size_t)i * DD + lane * 2);
    float s0 = a.x * a.x + a.y * a.y;
    float s1 = b.x * b.x + b.y * b.y;
    float d  = a.x * b.x + a.y * b.y;
    #pragma unroll
    for (int off = 32; off; off >>= 1) {
        s0 += __shfl_xor(s0, off);
        s1 += __shfl_xor(s1, off);
        d  += __shfl_xor(d,  off);
    }
    const float r0 = 1.0f / fmaxf(sqrtf(s0), 1e-12f);
    const float r1 = 1.0f / fmaxf(sqrtf(s1), 1e-12f);
    ushort2 t0; t0.x = f2bf(a.x * r0); t0.y = f2bf(a.y * r0);
    *(ushort2*)(n0b + (size_t)i * DD + lane * 2) = t0;
    const int p = pos[i];
    if (p >= 0) {
        const float sc = r1 * C_EXP2;
        ushort2 t1; t1.x = f2bf(b.x * sc); t1.y = f2bf(b.y * sc);
        *(ushort2*)(Bc + (size_t)p * DD + lane * 2) = t1;
        if (lane == 0) wc[p] = 1.0f;
    }
    if (lane == 0) diag[i] = d * r0 * r1;
}

// ---- main fused kernel: A in regs, B straight from global (no LDS) ------
// grid = (N/64)*JSL blocks x 256. Block = 64 i-rows x one col-slice.
// Wave w handles 16-col groups g = jsl*4 + w + 16*s. No barriers at all.
// Epilogue per group: dacc += exp2(acc) * wc[col]  (B pre-scaled by C_EXP2).
__global__ __launch_bounds__(256, 4) void gemm_kernel(
        const u16* __restrict__ n0b, const u16* __restrict__ Bc,
        const float* __restrict__ wc, const int* __restrict__ cnt,
        float* __restrict__ den) {
    const int tid  = threadIdx.x;
    const int wave = tid >> 6, lane = tid & 63;
    const int bid  = blockIdx.x;
    const int jsl  = bid & (JSL - 1);     // co-resident blocks: same slice
    const int iblk = bid >> 2;            // 0..255
    const int lr = lane & 15, lk = lane >> 4;

    const int c = *cnt;
    const int G = (c + 15) >> 4;          // 16-col groups

    // A fragments: 64 rows, resident in VGPRs for the whole kernel.
    bf16x8 af[4][4];
    #pragma unroll
    for (int m = 0; m < 4; ++m) {
        const int r = iblk * 64 + m * 16 + lr;
        const char* rowp = (const char*)(n0b + (size_t)r * DD);
        #pragma unroll
        for (int kk = 0; kk < 4; ++kk)
            af[m][kk] = *(const bf16x8*)(rowp + kk * 64 + lk * 16);
    }

    f32x4 dacc[4] = {};   // [m][reg] per-lane col-partial denominators

    for (int g = jsl * 4 + wave; g < G; g += 4 * JSL) {
        const int col = g * 16 + lr;
        const char* bp = (const char*)(Bc + (size_t)col * DD);
        bf16x8 bfr[4];
        #pragma unroll
        for (int kk = 0; kk < 4; ++kk)
            bfr[kk] = *(const bf16x8*)(bp + kk * 64 + lk * 16);
        const float wv = wc[col];

        f32x4 acc[4] = {};
        #pragma unroll
        for (int kk = 0; kk < 4; ++kk)
            #pragma unroll
            for (int m = 0; m < 4; ++m)
                acc[m] = __builtin_amdgcn_mfma_f32_16x16x32_bf16(
                             af[m][kk], bfr[kk], acc[m], 0, 0, 0);

        #pragma unroll
        for (int m = 0; m < 4; ++m)
            #pragma unroll
            for (int reg = 0; reg < 4; ++reg)
                dacc[m][reg] += fast_exp2(acc[m][reg]) * wv;
    }

    // reduce col-partials across the 16 lr-lanes; 1 atomic per (row, wave)
    #pragma unroll
    for (int m = 0; m < 4; ++m)
        #pragma unroll
        for (int reg = 0; reg < 4; ++reg) {
            float s = dacc[m][reg];
            s += __shfl_xor(s, 1);
            s += __shfl_xor(s, 2);
            s += __shfl_xor(s, 4);
            s += __shfl_xor(s, 8);
            if (lr == 0)
                atomicAdd(&den[iblk * 64 + m * 16 + lk * 4 + reg], s);
        }
}

// ---- final masked loss: partial reduce + double atomics + ticket --------
__global__ __launch_bounds__(256) void final_kernel(
        const float* __restrict__ diag, const float* __restrict__ den,
        const float* __restrict__ maskf, double* __restrict__ accum,
        int* __restrict__ ticket, float* __restrict__ out) {
    const int i = blockIdx.x * 256 + threadIdx.x;
    double ls = 0.0, cs = 0.0;
    const float m = maskf[i];
    if (m != 0.0f) {
        const float num = expf(diag[i] * INV_T);
        const float l = logf(den[i] + 1e-8f) - logf(num + 1e-8f);
        ls = (double)l;
        cs = 1.0;
    }
    #pragma unroll
    for (int off = 32; off; off >>= 1) {
        ls += __shfl_xor(ls, off);
        cs += __shfl_xor(cs, off);
    }
    __shared__ double sl[4], sc[4];
    const int wave = threadIdx.x >> 6, lane = threadIdx.x & 63;
    if (lane == 0) { sl[wave] = ls; sc[wave] = cs; }
    __syncthreads();
    if (threadIdx.x == 0) {
        atomicAdd(&accum[0], sl[0] + sl[1] + sl[2] + sl[3]);
        atomicAdd(&accum[1], sc[0] + sc[1] + sc[2] + sc[3]);
        __threadfence();
        const int t = atomicAdd(ticket, 1);
        if (t == (int)gridDim.x - 1) {
            const double L = atomicAdd(&accum[0], 0.0);
            const double C = atomicAdd(&accum[1], 0.0);
            out[0] = (float)(L / C);
        }
    }
}

extern "C" void kernel_launch(void* const* d_in, const int* in_sizes, int n_in,
                              void* d_out, int out_size, void* d_ws, size_t ws_size,
                              hipStream_t stream) {
    const float* f0 = (const float*)d_in[0];
    const float* f1 = (const float*)d_in[1];
    const u8*  mraw = (const u8*)d_in[2];
    float* out = (float*)d_out;

    const int N = in_sizes[2];            // 16384
    char* ws = (char*)d_ws;
    u16*   n0b   = (u16*)ws;
    u16*   Bc    = (u16*)(ws + (size_t)4 * 1024 * 1024);
    float* diag  = (float*)(ws + (size_t)8 * 1024 * 1024);
    float* maskf = diag + N;
    float* wc    = maskf + N;
    float* den   = wc + N;
    int*   pos   = (int*)(den + N);
    int*   cnt   = (int*)(pos + N);       // 8-aligned; [cnt, ticket]
    int*   ticket = cnt + 1;
    double* accum = (double*)(cnt + 2);   // [0]=loss sum, [1]=count

    hipMemsetAsync(cnt, 0, 2 * sizeof(int) + 2 * sizeof(double), stream);
    prep_kernel<<<N / 256, 256, 0, stream>>>(mraw, maskf, wc, den, pos, cnt, N);
    norm_kernel<<<N / 4, 256, 0, stream>>>(f0, f1, pos, n0b, Bc, wc, diag);
    gemm_kernel<<<dim3((N / 64) * JSL), 256, 0, stream>>>(n0b, Bc, wc, cnt, den);
    final_kernel<<<N / 256, 256, 0, stream>>>(diag, den, maskf, accum, ticket, out);
}

// Round 8
// 147.124 us; speedup vs baseline: 1.0256x; 1.0256x over previous
//
#include <hip/hip_runtime.h>
#include <hip/hip_bf16.h>

// SampleContrastiveLoss on MI355X — round 8.
// N = 16384, D = 128. den_i = sum_{j masked} exp(sim_ij / T).
// Round-8 delta (vs round-7 regression): round 7's VGPR_Count=56 proved the
// compiler rematerialized af[4][4] from global inside the loop under the
// launch_bounds(256,4) 128-VGPR cap -> 2.8 GB L2 traffic -> 77.6us (L2-BW
// bound; 2.8GB/34.5TB/s = 81us matches). Fix: pin af in VGPRs with opaque
// asm, relax to launch_bounds(256,3) (170-VGPR cap), JSL=3 -> grid 768 =
// exactly 3 blocks/CU in one dispatch round.
//
// ws layout:
//   [0,      4 MB)   n0b  bf16 [N][128]
//   [4 MB,   8 MB)   Bc   bf16 [N][128]  (compacted masked n1 rows, scaled)
//   [8 MB, ...)      diag f32[N] | maskf f32[N] | wc f32[N] | den f32[N]
//                    | pos i32[N] | {cnt i32, ticket i32, Lsum f64, Csum f64}

#define DD 128
#define INV_T 14.285714285714286f
#define C_EXP2 20.6099291555566f   // INV_T * log2(e)
#define JSL 3                      // col-slices; grid = (N/64)*JSL = 768

typedef __attribute__((ext_vector_type(8))) short bf16x8; // 8 bf16 = 4 VGPR
typedef __attribute__((ext_vector_type(4))) float f32x4;
typedef unsigned short u16;
typedef unsigned char u8;

__device__ __forceinline__ u16 f2bf(float x) {   // RNE f32->bf16
    union { float f; unsigned u; } v; v.f = x;
    unsigned r = v.u + 0x7fffu + ((v.u >> 16) & 1u);
    return (u16)(r >> 16);
}

__device__ __forceinline__ float fast_exp2(float x) {
#if __has_builtin(__builtin_amdgcn_exp2f)
    return __builtin_amdgcn_exp2f(x);     // raw v_exp_f32
#else
    return exp2f(x);
#endif
}

// ---- mask dtype detect + maskf/wc/den init + block-scan compaction ------
// bool-as-u8: bytes at p%4!=0 in the first 4KB are ~50% nonzero.
// int32 0/1 LE: those bytes are all zero. Every block derives the same flag.
__global__ __launch_bounds__(256) void prep_kernel(
        const u8* __restrict__ mraw, float* __restrict__ maskf,
        float* __restrict__ wc, float* __restrict__ den,
        int* __restrict__ pos, int* __restrict__ cnt, int n) {
    __shared__ int s_any;
    __shared__ int s_wsum[4];
    __shared__ int s_base;
    if (threadIdx.x == 0) s_any = 0;
    __syncthreads();
    int local = 0;
    #pragma unroll
    for (int q = 0; q < 16; ++q) {
        const int p = threadIdx.x * 16 + q;
        if ((p & 3) && mraw[p]) local = 1;
    }
    if (local) atomicOr(&s_any, 1);
    __syncthreads();
    const bool is_u8 = (s_any != 0);
    const int* mi = (const int*)mraw;

    const int i = blockIdx.x * 256 + threadIdx.x;
    const int v = is_u8 ? (int)mraw[i] : mi[i];
    const int m = v ? 1 : 0;
    maskf[i] = (float)m;
    wc[i]   = 0.0f;
    den[i]  = 0.0f;

    const int wave = threadIdx.x >> 6, lane = threadIdx.x & 63;
    const unsigned long long bal = __ballot(m);
    const int wprefix = __popcll(bal & ((1ULL << lane) - 1ULL));
    const int wtotal  = __popcll(bal);
    if (lane == 0) s_wsum[wave] = wtotal;
    __syncthreads();
    if (threadIdx.x == 0)
        s_base = atomicAdd(cnt, s_wsum[0] + s_wsum[1] + s_wsum[2] + s_wsum[3]);
    __syncthreads();
    int wbase = 0;
    #pragma unroll
    for (int w = 0; w < 4; ++w)
        if (w < wave) wbase += s_wsum[w];
    pos[i] = m ? (s_base + wbase + wprefix) : -1;
}

// ---- per-row L2 normalize; write A (bf16), scatter masked scaled B ------
__global__ __launch_bounds__(256) void norm_kernel(
        const float* __restrict__ f0, const float* __restrict__ f1,
        const int* __restrict__ pos,
        u16* __restrict__ n0b, u16* __restrict__ Bc, float* __restrict__ wc,
        float* __restrict__ diag) {
    const int wave = threadIdx.x >> 6, lane = threadIdx.x & 63;
    const int i = blockIdx.x * 4 + wave;
    const float2 a = *(const float2*)(f0 + (size_t)i * DD + lane * 2);
    const float2 b = *(const float2*)(f1 + (size_t)i * DD + lane * 2);
    float s0 = a.x * a.x + a.y * a.y;
    float s1 = b.x * b.x + b.y * b.y;
    float d  = a.x * b.x + a.y * b.y;
    #pragma unroll
    for (int off = 32; off; off >>= 1) {
        s0 += __shfl_xor(s0, off);
        s1 += __shfl_xor(s1, off);
        d  += __shfl_xor(d,  off);
    }
    const float r0 = 1.0f / fmaxf(sqrtf(s0), 1e-12f);
    const float r1 = 1.0f / fmaxf(sqrtf(s1), 1e-12f);
    ushort2 t0; t0.x = f2bf(a.x * r0); t0.y = f2bf(a.y * r0);
    *(ushort2*)(n0b + (size_t)i * DD + lane * 2) = t0;
    const int p = pos[i];
    if (p >= 0) {
        const float sc = r1 * C_EXP2;
        ushort2 t1; t1.x = f2bf(b.x * sc); t1.y = f2bf(b.y * sc);
        *(ushort2*)(Bc + (size_t)p * DD + lane * 2) = t1;
        if (lane == 0) wc[p] = 1.0f;
    }
    if (lane == 0) diag[i] = d * r0 * r1;
}

// ---- main fused kernel: A pinned in regs, B straight from global --------
// grid = (N/64)*JSL blocks x 256. Block = 64 i-rows x one col-slice.
// Wave w in slice jsl handles groups g = 4*jsl + w (mod 12). No barriers.
// Epilogue per group: dacc += exp2(acc) * wc[col]  (B pre-scaled by C_EXP2).
__global__ __launch_bounds__(256, 3) void gemm_kernel(
        const u16* __restrict__ n0b, const u16* __restrict__ Bc,
        const float* __restrict__ wc, const int* __restrict__ cnt,
        float* __restrict__ den) {
    const int tid  = threadIdx.x;
    const int wave = tid >> 6, lane = tid & 63;
    const int bid  = blockIdx.x;
    const int jsl  = bid % JSL;
    const int iblk = bid / JSL;           // 0..255
    const int lr = lane & 15, lk = lane >> 4;

    const int c = *cnt;
    const int G = (c + 15) >> 4;          // 16-col groups

    // A fragments: 64 rows, PINNED resident in VGPRs for the whole kernel.
    bf16x8 af[4][4];
    #pragma unroll
    for (int m = 0; m < 4; ++m) {
        const int r = iblk * 64 + m * 16 + lr;
        const char* rowp = (const char*)(n0b + (size_t)r * DD);
        #pragma unroll
        for (int kk = 0; kk < 4; ++kk)
            af[m][kk] = *(const bf16x8*)(rowp + kk * 64 + lk * 16);
    }
    // Opaque pin: forbids rematerialization-from-global (round-7 failure
    // mode: VGPR_Count=56 proved af was reloaded every iteration -> 2.8 GB
    // of L2 traffic). After this asm, af must live in VGPRs.
    #pragma unroll
    for (int m = 0; m < 4; ++m)
        #pragma unroll
        for (int kk = 0; kk < 4; ++kk)
            asm volatile("" : "+v"(af[m][kk]));

    f32x4 dacc[4] = {};   // [m][reg] per-lane col-partial denominators

    for (int g = jsl * 4 + wave; g < G; g += 4 * JSL) {
        const int col = g * 16 + lr;
        const char* bp = (const char*)(Bc + (size_t)col * DD);
        bf16x8 bfr[4];
        #pragma unroll
        for (int kk = 0; kk < 4; ++kk)
            bfr[kk] = *(const bf16x8*)(bp + kk * 64 + lk * 16);
        const float wv = wc[col];

        f32x4 acc[4] = {};
        #pragma unroll
        for (int kk = 0; kk < 4; ++kk)
            #pragma unroll
            for (int m = 0; m < 4; ++m)
                acc[m] = __builtin_amdgcn_mfma_f32_16x16x32_bf16(
                             af[m][kk], bfr[kk], acc[m], 0, 0, 0);

        #pragma unroll
        for (int m = 0; m < 4; ++m)
            #pragma unroll
            for (int reg = 0; reg < 4; ++reg)
                dacc[m][reg] += fast_exp2(acc[m][reg]) * wv;
    }

    // reduce col-partials across the 16 lr-lanes; 1 atomic per (row, wave)
    #pragma unroll
    for (int m = 0; m < 4; ++m)
        #pragma unroll
        for (int reg = 0; reg < 4; ++reg) {
            float s = dacc[m][reg];
            s += __shfl_xor(s, 1);
            s += __shfl_xor(s, 2);
            s += __shfl_xor(s, 4);
            s += __shfl_xor(s, 8);
            if (lr == 0)
                atomicAdd(&den[iblk * 64 + m * 16 + lk * 4 + reg], s);
        }
}

// ---- final masked loss: partial reduce + double atomics + ticket --------
__global__ __launch_bounds__(256) void final_kernel(
        const float* __restrict__ diag, const float* __restrict__ den,
        const float* __restrict__ maskf, double* __restrict__ accum,
        int* __restrict__ ticket, float* __restrict__ out) {
    const int i = blockIdx.x * 256 + threadIdx.x;
    double ls = 0.0, cs = 0.0;
    const float m = maskf[i];
    if (m != 0.0f) {
        const float num = expf(diag[i] * INV_T);
        const float l = logf(den[i] + 1e-8f) - logf(num + 1e-8f);
        ls = (double)l;
        cs = 1.0;
    }
    #pragma unroll
    for (int off = 32; off; off >>= 1) {
        ls += __shfl_xor(ls, off);
        cs += __shfl_xor(cs, off);
    }
    __shared__ double sl[4], sc[4];
    const int wave = threadIdx.x >> 6, lane = threadIdx.x & 63;
    if (lane == 0) { sl[wave] = ls; sc[wave] = cs; }
    __syncthreads();
    if (threadIdx.x == 0) {
        atomicAdd(&accum[0], sl[0] + sl[1] + sl[2] + sl[3]);
        atomicAdd(&accum[1], sc[0] + sc[1] + sc[2] + sc[3]);
        __threadfence();
        const int t = atomicAdd(ticket, 1);
        if (t == (int)gridDim.x - 1) {
            const double L = atomicAdd(&accum[0], 0.0);
            const double C = atomicAdd(&accum[1], 0.0);
            out[0] = (float)(L / C);
        }
    }
}

extern "C" void kernel_launch(void* const* d_in, const int* in_sizes, int n_in,
                              void* d_out, int out_size, void* d_ws, size_t ws_size,
                              hipStream_t stream) {
    const float* f0 = (const float*)d_in[0];
    const float* f1 = (const float*)d_in[1];
    const u8*  mraw = (const u8*)d_in[2];
    float* out = (float*)d_out;

    const int N = in_sizes[2];            // 16384
    char* ws = (char*)d_ws;
    u16*   n0b   = (u16*)ws;
    u16*   Bc    = (u16*)(ws + (size_t)4 * 1024 * 1024);
    float* diag  = (float*)(ws + (size_t)8 * 1024 * 1024);
    float* maskf = diag + N;
    float* wc    = maskf + N;
    float* den   = wc + N;
    int*   pos   = (int*)(den + N);
    int*   cnt   = (int*)(pos + N);       // 8-aligned; [cnt, ticket]
    int*   ticket = cnt + 1;
    double* accum = (double*)(cnt + 2);   // [0]=loss sum, [1]=count

    hipMemsetAsync(cnt, 0, 2 * sizeof(int) + 2 * sizeof(double), stream);
    prep_kernel<<<N / 256, 256, 0, stream>>>(mraw, maskf, wc, den, pos, cnt, N);
    norm_kernel<<<N / 4, 256, 0, stream>>>(f0, f1, pos, n0b, Bc, wc, diag);
    gemm_kernel<<<dim3((N / 64) * JSL), 256, 0, stream>>>(n0b, Bc, wc, cnt, den);
    final_kernel<<<N / 256, 256, 0, stream>>>(diag, den, maskf, accum, ticket, out);
}